// Round 15
// baseline (102.420 us; speedup 1.0000x reference)
//
#include <hip/hip_runtime.h>
#include <hip/hip_bf16.h>

#define NPTS 8192
#define DDIM 128
#define MARGIN 0.2f
#define NEG_FLOOR 0.6f
#define SENT -1e30f
#define NCHUNK 16
#define CHUNK (NPTS / NCHUNK)      // 512 cols per chunk
#define BM 128                     // rows per block (4 waves x 32)
#define JT 64                      // cols staged per step
#define NSTEP (CHUNK / JT)         // 8
#define NRB (NPTS / 256)           // 32 reduce blocks

typedef __attribute__((ext_vector_type(8))) short short8;
typedef __attribute__((ext_vector_type(4))) float f32x4;
typedef __attribute__((ext_vector_type(4))) unsigned int uint4v;
typedef __attribute__((ext_vector_type(4))) unsigned short ushort4v;

// ws layout: xb 2MiB | partA 512K | partB 512K | maxpos 32K | maxneg 32K | blksum/cnt

__device__ __forceinline__ unsigned short f2bf(unsigned u) {
    return (unsigned short)((u + 0x7FFFu + ((u >> 16) & 1u)) >> 16);
}

__global__ __launch_bounds__(256) void k_convert(const uint4v* __restrict__ x,
                                                 ushort4v* __restrict__ xb) {
    int i = blockIdx.x * 256 + threadIdx.x;
    uint4v u = x[i];
    ushort4v o;
    o.x = f2bf(u.x); o.y = f2bf(u.y); o.z = f2bf(u.z); o.w = f2bf(u.w);
    xb[i] = o;
}

__device__ __forceinline__ void gload16(const unsigned char* g, unsigned char* l) {
    __builtin_amdgcn_global_load_lds(
        (const __attribute__((address_space(1))) unsigned int*)(const void*)g,
        (__attribute__((address_space(3))) unsigned int*)(void*)l, 16, 0, 0);
}

// LDS B-tile layout = fragment order: slot(cg, ks, lane) at byte
// cg*4096 + ks*1024 + lane*16 holds global bytes
// (j0 + cg*16 + (lane&15))*256 + ks*64 + (lane>>4)*16.
// Wave w stages cg=w; every hot ds_read_b128 is base + lane*16 (conflict-free).

// Paired col-groups: 4 independent MFMA chains (acc[rg][cgl]) per pair.
#define MFMA_PAIR(B_, cg0_)                                                           \
    short8 bA0 = *(const short8*)((B_) + (cg0_)*4096 + 0 * 1024 + lane * 16);         \
    short8 bA1 = *(const short8*)((B_) + (cg0_)*4096 + 1 * 1024 + lane * 16);         \
    short8 bA2 = *(const short8*)((B_) + (cg0_)*4096 + 2 * 1024 + lane * 16);         \
    short8 bA3 = *(const short8*)((B_) + (cg0_)*4096 + 3 * 1024 + lane * 16);         \
    short8 bB0 = *(const short8*)((B_) + (cg0_)*4096 + 4096 + 0 * 1024 + lane * 16);  \
    short8 bB1 = *(const short8*)((B_) + (cg0_)*4096 + 4096 + 1 * 1024 + lane * 16);  \
    short8 bB2 = *(const short8*)((B_) + (cg0_)*4096 + 4096 + 2 * 1024 + lane * 16);  \
    short8 bB3 = *(const short8*)((B_) + (cg0_)*4096 + 4096 + 3 * 1024 + lane * 16);  \
    f32x4 accA0 = {0.f,0.f,0.f,0.f}, accA1 = {0.f,0.f,0.f,0.f};                       \
    f32x4 accB0 = {0.f,0.f,0.f,0.f}, accB1 = {0.f,0.f,0.f,0.f};                       \
    accA0 = __builtin_amdgcn_mfma_f32_16x16x32_bf16(a[0][0], bA0, accA0, 0, 0, 0);    \
    accA1 = __builtin_amdgcn_mfma_f32_16x16x32_bf16(a[1][0], bA0, accA1, 0, 0, 0);    \
    accB0 = __builtin_amdgcn_mfma_f32_16x16x32_bf16(a[0][0], bB0, accB0, 0, 0, 0);    \
    accB1 = __builtin_amdgcn_mfma_f32_16x16x32_bf16(a[1][0], bB0, accB1, 0, 0, 0);    \
    accA0 = __builtin_amdgcn_mfma_f32_16x16x32_bf16(a[0][1], bA1, accA0, 0, 0, 0);    \
    accA1 = __builtin_amdgcn_mfma_f32_16x16x32_bf16(a[1][1], bA1, accA1, 0, 0, 0);    \
    accB0 = __builtin_amdgcn_mfma_f32_16x16x32_bf16(a[0][1], bB1, accB0, 0, 0, 0);    \
    accB1 = __builtin_amdgcn_mfma_f32_16x16x32_bf16(a[1][1], bB1, accB1, 0, 0, 0);    \
    accA0 = __builtin_amdgcn_mfma_f32_16x16x32_bf16(a[0][2], bA2, accA0, 0, 0, 0);    \
    accA1 = __builtin_amdgcn_mfma_f32_16x16x32_bf16(a[1][2], bA2, accA1, 0, 0, 0);    \
    accB0 = __builtin_amdgcn_mfma_f32_16x16x32_bf16(a[0][2], bB2, accB0, 0, 0, 0);    \
    accB1 = __builtin_amdgcn_mfma_f32_16x16x32_bf16(a[1][2], bB2, accB1, 0, 0, 0);    \
    accA0 = __builtin_amdgcn_mfma_f32_16x16x32_bf16(a[0][3], bA3, accA0, 0, 0, 0);    \
    accA1 = __builtin_amdgcn_mfma_f32_16x16x32_bf16(a[1][3], bA3, accA1, 0, 0, 0);    \
    accB0 = __builtin_amdgcn_mfma_f32_16x16x32_bf16(a[0][3], bB3, accB0, 0, 0, 0);    \
    accB1 = __builtin_amdgcn_mfma_f32_16x16x32_bf16(a[1][3], bB3, accB1, 0, 0, 0);

__global__ __launch_bounds__(256, 4) void k_pass1(const unsigned short* __restrict__ xb,
                                                  const int* __restrict__ tg,
                                                  float* __restrict__ mp_part,
                                                  float* __restrict__ mn_part) {
    __shared__ __align__(16) unsigned char smB[JT * 256];  // 16 KB
    __shared__ int ts[CHUNK];                              // 2 KB

    const unsigned char* xc = (const unsigned char*)xb;
    int tid  = threadIdx.x;
    int lane = tid & 63, w = tid >> 6, lr = lane & 15, hi = lane >> 4;
    int bb    = blockIdx.x;
    int chunk = bb & (NCHUNK - 1);
    int rb    = bb >> 4;
    int jbase = chunk * CHUNK;
    int rowbase = rb * BM + w * 32;

    ts[tid]       = tg[jbase + tid];
    ts[tid + 256] = tg[jbase + 256 + tid];

    short8 a[2][4];
#pragma unroll
    for (int rg = 0; rg < 2; ++rg)
#pragma unroll
        for (int ks = 0; ks < 4; ++ks)
            a[rg][ks] = *(const short8*)(xc + (size_t)(rowbase + rg * 16 + lr) * 256 + ks * 64 + hi * 16);

    int trow[2][4];
#pragma unroll
    for (int rg = 0; rg < 2; ++rg)
#pragma unroll
        for (int r = 0; r < 4; ++r)
            trow[rg][r] = tg[rowbase + rg * 16 + hi * 4 + r];

    float mp[2][4], mn[2][4];
#pragma unroll
    for (int rg = 0; rg < 2; ++rg)
#pragma unroll
        for (int r = 0; r < 4; ++r) { mp[rg][r] = SENT; mn[rg][r] = SENT; }

    for (int step = 0; step < NSTEP; ++step) {
        int j0 = jbase + step * JT;
        __syncthreads();  // prior compute done (iter 0: ts ready)
        const unsigned char* src = xc + (size_t)(j0 + w * 16 + lr) * 256 + hi * 16;
#pragma unroll
        for (int r = 0; r < 4; ++r)
            gload16(src + r * 64, smB + w * 4096 + r * 1024);
        __syncthreads();  // tile ready

        bool dstep = (unsigned)(rowbase - j0) < (unsigned)JT;
#pragma unroll
        for (int cgp = 0; cgp < 2; ++cgp) {
            int cg0 = cgp * 2;
            int tjA = ts[step * 64 + cg0 * 16 + lr];
            int tjB = ts[step * 64 + cg0 * 16 + 16 + lr];
            MFMA_PAIR(smB, cg0)
            if (dstep) {
#pragma unroll
                for (int rg = 0; rg < 2; ++rg) {
                    f32x4 aA = (rg == 0) ? accA0 : accA1;
                    f32x4 aB = (rg == 0) ? accB0 : accB1;
                    int base = rowbase + rg * 16 + hi * 4;
                    int dvA = j0 + cg0 * 16 + lr - base;
                    int dvB = dvA + 16;
#pragma unroll
                    for (int r = 0; r < 4; ++r) {
                        bool sA = (tjA == trow[rg][r]);
                        bool sB = (tjB == trow[rg][r]);
                        mp[rg][r] = fmaxf(mp[rg][r], (sA && dvA != r) ? aA[r] : SENT);
                        mn[rg][r] = fmaxf(mn[rg][r], sA ? SENT : aA[r]);
                        mp[rg][r] = fmaxf(mp[rg][r], (sB && dvB != r) ? aB[r] : SENT);
                        mn[rg][r] = fmaxf(mn[rg][r], sB ? SENT : aB[r]);
                    }
                }
            } else {
#pragma unroll
                for (int rg = 0; rg < 2; ++rg) {
                    f32x4 aA = (rg == 0) ? accA0 : accA1;
                    f32x4 aB = (rg == 0) ? accB0 : accB1;
#pragma unroll
                    for (int r = 0; r < 4; ++r) {
                        bool sA = (tjA == trow[rg][r]);
                        bool sB = (tjB == trow[rg][r]);
                        mp[rg][r] = fmaxf(mp[rg][r], sA ? aA[r] : SENT);
                        mn[rg][r] = fmaxf(mn[rg][r], sA ? SENT : aA[r]);
                        mp[rg][r] = fmaxf(mp[rg][r], sB ? aB[r] : SENT);
                        mn[rg][r] = fmaxf(mn[rg][r], sB ? SENT : aB[r]);
                    }
                }
            }
        }
    }

#pragma unroll
    for (int off = 1; off < 16; off <<= 1)
#pragma unroll
        for (int rg = 0; rg < 2; ++rg)
#pragma unroll
            for (int r = 0; r < 4; ++r) {
                mp[rg][r] = fmaxf(mp[rg][r], __shfl_xor(mp[rg][r], off, 64));
                mn[rg][r] = fmaxf(mn[rg][r], __shfl_xor(mn[rg][r], off, 64));
            }
    if (lr == 0) {
#pragma unroll
        for (int rg = 0; rg < 2; ++rg)
#pragma unroll
            for (int r = 0; r < 4; ++r) {
                int row = rowbase + rg * 16 + hi * 4 + r;
                mp_part[chunk * NPTS + row] = mp[rg][r];
                mn_part[chunk * NPTS + row] = mn[rg][r];
            }
    }
}

__global__ __launch_bounds__(256) void k_red1(const float* __restrict__ mp_part,
                                              const float* __restrict__ mn_part,
                                              float* __restrict__ maxpos,
                                              float* __restrict__ maxneg) {
    int row = blockIdx.x * 256 + threadIdx.x;
    float mp = SENT, mn = SENT;
#pragma unroll
    for (int c = 0; c < NCHUNK; ++c) {
        mp = fmaxf(mp, mp_part[c * NPTS + row]);
        mn = fmaxf(mn, mn_part[c * NPTS + row]);
    }
    maxpos[row] = mp;
    maxneg[row] = mn;
}

__global__ __launch_bounds__(256, 4) void k_pass2(const unsigned short* __restrict__ xb,
                                                  const int* __restrict__ tg,
                                                  const float* __restrict__ maxpos,
                                                  const float* __restrict__ maxneg,
                                                  float* __restrict__ sum_part,
                                                  int* __restrict__ flg_part) {
    __shared__ __align__(16) unsigned char smB[JT * 256];
    __shared__ int ts[CHUNK];

    const unsigned char* xc = (const unsigned char*)xb;
    int tid  = threadIdx.x;
    int lane = tid & 63, w = tid >> 6, lr = lane & 15, hi = lane >> 4;
    int bb    = blockIdx.x;
    int chunk = bb & (NCHUNK - 1);
    int rb    = bb >> 4;
    int jbase = chunk * CHUNK;
    int rowbase = rb * BM + w * 32;

    ts[tid]       = tg[jbase + tid];
    ts[tid + 256] = tg[jbase + 256 + tid];

    short8 a[2][4];
#pragma unroll
    for (int rg = 0; rg < 2; ++rg)
#pragma unroll
        for (int ks = 0; ks < 4; ++ks)
            a[rg][ks] = *(const short8*)(xc + (size_t)(rowbase + rg * 16 + lr) * 256 + ks * 64 + hi * 16);

    int trow[2][4];
    float pos_lim[2][4], neg_th[2][4];
#pragma unroll
    for (int rg = 0; rg < 2; ++rg)
#pragma unroll
        for (int r = 0; r < 4; ++r) {
            int row         = rowbase + rg * 16 + hi * 4 + r;
            trow[rg][r]     = tg[row];
            pos_lim[rg][r]  = maxneg[row] + MARGIN;
            neg_th[rg][r]   = fmaxf(NEG_FLOOR, maxpos[row]) - MARGIN;
        }

    float sumP[2][4] = {{0.f,0.f,0.f,0.f},{0.f,0.f,0.f,0.f}};
    float sumN[2][4] = {{0.f,0.f,0.f,0.f},{0.f,0.f,0.f,0.f}};

    for (int step = 0; step < NSTEP; ++step) {
        int j0 = jbase + step * JT;
        __syncthreads();
        const unsigned char* src = xc + (size_t)(j0 + w * 16 + lr) * 256 + hi * 16;
#pragma unroll
        for (int r = 0; r < 4; ++r)
            gload16(src + r * 64, smB + w * 4096 + r * 1024);
        __syncthreads();

        bool dstep = (unsigned)(rowbase - j0) < (unsigned)JT;
#pragma unroll
        for (int cgp = 0; cgp < 2; ++cgp) {
            int cg0 = cgp * 2;
            int tjA = ts[step * 64 + cg0 * 16 + lr];
            int tjB = ts[step * 64 + cg0 * 16 + 16 + lr];
            MFMA_PAIR(smB, cg0)
            if (dstep) {
#pragma unroll
                for (int rg = 0; rg < 2; ++rg) {
                    f32x4 aA = (rg == 0) ? accA0 : accA1;
                    f32x4 aB = (rg == 0) ? accB0 : accB1;
                    int base = rowbase + rg * 16 + hi * 4;
                    int dvA = j0 + cg0 * 16 + lr - base;
                    int dvB = dvA + 16;
#pragma unroll
                    for (int r = 0; r < 4; ++r) {
                        bool sA = (tjA == trow[rg][r]);
                        bool sB = (tjB == trow[rg][r]);
                        float vA = aA[r], vB = aB[r];
                        bool pA = sA && (dvA != r) && (vA < pos_lim[rg][r]);
                        bool nA = (!sA) && (vA > neg_th[rg][r]);
                        bool pB = sB && (dvB != r) && (vB < pos_lim[rg][r]);
                        bool nB = (!sB) && (vB > neg_th[rg][r]);
                        sumP[rg][r] += (pA ? (1.0f - vA) : 0.0f) + (pB ? (1.0f - vB) : 0.0f);
                        sumN[rg][r] += (nA ? vA : 0.0f) + (nB ? vB : 0.0f);
                    }
                }
            } else {
#pragma unroll
                for (int rg = 0; rg < 2; ++rg) {
                    f32x4 aA = (rg == 0) ? accA0 : accA1;
                    f32x4 aB = (rg == 0) ? accB0 : accB1;
#pragma unroll
                    for (int r = 0; r < 4; ++r) {
                        bool sA = (tjA == trow[rg][r]);
                        bool sB = (tjB == trow[rg][r]);
                        float vA = aA[r], vB = aB[r];
                        bool pA = sA && (vA < pos_lim[rg][r]);
                        bool nA = (!sA) && (vA > neg_th[rg][r]);
                        bool pB = sB && (vB < pos_lim[rg][r]);
                        bool nB = (!sB) && (vB > neg_th[rg][r]);
                        sumP[rg][r] += (pA ? (1.0f - vA) : 0.0f) + (pB ? (1.0f - vB) : 0.0f);
                        sumN[rg][r] += (nA ? vA : 0.0f) + (nB ? vB : 0.0f);
                    }
                }
            }
        }
    }

    // any selected negative <=> sumN > 0 (selected negs have s > 0.4)
    float sum[2][4];
    int an = 0;
#pragma unroll
    for (int rg = 0; rg < 2; ++rg)
#pragma unroll
        for (int r = 0; r < 4; ++r) {
            sum[rg][r] = sumP[rg][r] + sumN[rg][r];
            an |= (sumN[rg][r] > 0.f) ? (1 << (rg * 4 + r)) : 0;
        }

#pragma unroll
    for (int off = 1; off < 16; off <<= 1) {
        an |= __shfl_xor(an, off, 64);
#pragma unroll
        for (int rg = 0; rg < 2; ++rg)
#pragma unroll
            for (int r = 0; r < 4; ++r)
                sum[rg][r] += __shfl_xor(sum[rg][r], off, 64);
    }
    if (lr == 0) {
#pragma unroll
        for (int rg = 0; rg < 2; ++rg)
#pragma unroll
            for (int r = 0; r < 4; ++r) {
                int row = rowbase + rg * 16 + hi * 4 + r;
                sum_part[chunk * NPTS + row] = sum[rg][r];
                flg_part[chunk * NPTS + row] = (an >> (rg * 4 + r)) & 1;
            }
    }
}

__global__ __launch_bounds__(256) void k_red2(const float* __restrict__ maxpos,
                                              const float* __restrict__ sum_part,
                                              const int* __restrict__ flg_part,
                                              float* __restrict__ blksum,
                                              float* __restrict__ blkcnt) {
    __shared__ float sf[256];
    __shared__ int   si[256];
    int t   = threadIdx.x;
    int row = blockIdx.x * 256 + t;

    bool hp = maxpos[row] > -1e29f;
    float rs = 0.f;
    int   fl = 0;
#pragma unroll
    for (int ch = 0; ch < NCHUNK; ++ch) {
        rs += sum_part[ch * NPTS + row];
        fl |= flg_part[ch * NPTS + row];
    }
    sf[t] = hp ? rs : 0.f;
    si[t] = (hp && fl) ? 1 : 0;
    __syncthreads();
    for (int off = 128; off > 0; off >>= 1) {
        if (t < off) { sf[t] += sf[t + off]; si[t] += si[t + off]; }
        __syncthreads();
    }
    if (t == 0) {
        blksum[blockIdx.x] = sf[0];
        blkcnt[blockIdx.x] = (float)si[0];
    }
}

__global__ __launch_bounds__(64) void k_final(const float* __restrict__ blksum,
                                              const float* __restrict__ blkcnt,
                                              float* __restrict__ out) {
    int t = threadIdx.x;
    float s = (t < NRB) ? blksum[t] : 0.f;
    float c = (t < NRB) ? blkcnt[t] : 0.f;
#pragma unroll
    for (int off = 32; off > 0; off >>= 1) {
        s += __shfl_xor(s, off, 64);
        c += __shfl_xor(c, off, 64);
    }
    if (t == 0) {
        out[0] = s / (float)NPTS;
        out[1] = c;
    }
}

extern "C" void kernel_launch(void* const* d_in, const int* in_sizes, int n_in,
                              void* d_out, int out_size, void* d_ws, size_t ws_size,
                              hipStream_t stream) {
    const float* x  = (const float*)d_in[0];
    const int*   tg = (const int*)d_in[1];
    float* out = (float*)d_out;

    unsigned short* xb = (unsigned short*)d_ws;
    char* base = (char*)d_ws + (size_t)NPTS * DDIM * 2;
    float* partA = (float*)(base);                                  // mp_part / sum_part
    float* partB = (float*)(base + (size_t)NCHUNK * NPTS * 4);      // mn_part / flg_part
    float* maxpos = (float*)(base + 2 * (size_t)NCHUNK * NPTS * 4);
    float* maxneg = (float*)(base + 2 * (size_t)NCHUNK * NPTS * 4 + NPTS * 4);
    float* blksum = (float*)(base + 2 * (size_t)NCHUNK * NPTS * 4 + 2 * NPTS * 4);
    float* blkcnt = blksum + NRB;

    k_convert<<<(NPTS * DDIM / 4) / 256, 256, 0, stream>>>((const uint4v*)x, (ushort4v*)xb);
    k_pass1<<<(NPTS / BM) * NCHUNK, 256, 0, stream>>>(xb, tg, partA, partB);
    k_red1<<<NPTS / 256, 256, 0, stream>>>(partA, partB, maxpos, maxneg);
    k_pass2<<<(NPTS / BM) * NCHUNK, 256, 0, stream>>>(xb, tg, maxpos, maxneg, partA, (int*)partB);
    k_red2<<<NRB, 256, 0, stream>>>(maxpos, partA, (const int*)partB, blksum, blkcnt);
    k_final<<<1, 64, 0, stream>>>(blksum, blkcnt, out);
}

// Round 16
// 75.968 us; speedup vs baseline: 1.3482x; 1.3482x over previous
//
#include <hip/hip_runtime.h>
#include <hip/hip_bf16.h>

#define NPTS 8192
#define DDIM 128
#define MARGIN 0.2f
#define NEG_FLOOR 0.6f
#define SENT -1e30f
#define NCHUNK 16
#define CHUNK (NPTS / NCHUNK)      // 512 cols per chunk
#define BM 128                     // rows per block (4 waves x 32)
#define JT 64                      // cols staged per step
#define NSTEP (CHUNK / JT)         // 8
#define NRB (NPTS / 256)           // 32 reduce blocks

typedef __attribute__((ext_vector_type(8))) short short8;
typedef __attribute__((ext_vector_type(4))) float f32x4;
typedef __attribute__((ext_vector_type(4))) unsigned int uint4v;
typedef __attribute__((ext_vector_type(4))) unsigned short ushort4v;

// ws layout: xb 2MiB | partA 512K | partB 512K | maxpos 32K | maxneg 32K | blksum/cnt

__device__ __forceinline__ unsigned short f2bf(unsigned u) {
    return (unsigned short)((u + 0x7FFFu + ((u >> 16) & 1u)) >> 16);
}

__global__ __launch_bounds__(256) void k_convert(const uint4v* __restrict__ x,
                                                 ushort4v* __restrict__ xb) {
    int i = blockIdx.x * 256 + threadIdx.x;
    uint4v u = x[i];
    ushort4v o;
    o.x = f2bf(u.x); o.y = f2bf(u.y); o.z = f2bf(u.z); o.w = f2bf(u.w);
    xb[i] = o;
}

__device__ __forceinline__ void gload16(const unsigned char* g, unsigned char* l) {
    __builtin_amdgcn_global_load_lds(
        (const __attribute__((address_space(1))) unsigned int*)(const void*)g,
        (__attribute__((address_space(3))) unsigned int*)(void*)l, 16, 0, 0);
}

// LDS B-tile layout = fragment order: slot(cg, ks, lane) at byte
// cg*4096 + ks*1024 + lane*16 holds global bytes
// (j0 + cg*16 + (lane&15))*256 + ks*64 + (lane>>4)*16.
// Wave w stages cg=w; every hot ds_read_b128 is base + lane*16 (conflict-free).

// Paired col-groups: 4 independent MFMA chains (acc[rg][cgl]) per pair.
#define MFMA_PAIR(B_, cg0_)                                                           \
    short8 bA0 = *(const short8*)((B_) + (cg0_)*4096 + 0 * 1024 + lane * 16);         \
    short8 bA1 = *(const short8*)((B_) + (cg0_)*4096 + 1 * 1024 + lane * 16);         \
    short8 bA2 = *(const short8*)((B_) + (cg0_)*4096 + 2 * 1024 + lane * 16);         \
    short8 bA3 = *(const short8*)((B_) + (cg0_)*4096 + 3 * 1024 + lane * 16);         \
    short8 bB0 = *(const short8*)((B_) + (cg0_)*4096 + 4096 + 0 * 1024 + lane * 16);  \
    short8 bB1 = *(const short8*)((B_) + (cg0_)*4096 + 4096 + 1 * 1024 + lane * 16);  \
    short8 bB2 = *(const short8*)((B_) + (cg0_)*4096 + 4096 + 2 * 1024 + lane * 16);  \
    short8 bB3 = *(const short8*)((B_) + (cg0_)*4096 + 4096 + 3 * 1024 + lane * 16);  \
    f32x4 accA0 = {0.f,0.f,0.f,0.f}, accA1 = {0.f,0.f,0.f,0.f};                       \
    f32x4 accB0 = {0.f,0.f,0.f,0.f}, accB1 = {0.f,0.f,0.f,0.f};                       \
    accA0 = __builtin_amdgcn_mfma_f32_16x16x32_bf16(a[0][0], bA0, accA0, 0, 0, 0);    \
    accA1 = __builtin_amdgcn_mfma_f32_16x16x32_bf16(a[1][0], bA0, accA1, 0, 0, 0);    \
    accB0 = __builtin_amdgcn_mfma_f32_16x16x32_bf16(a[0][0], bB0, accB0, 0, 0, 0);    \
    accB1 = __builtin_amdgcn_mfma_f32_16x16x32_bf16(a[1][0], bB0, accB1, 0, 0, 0);    \
    accA0 = __builtin_amdgcn_mfma_f32_16x16x32_bf16(a[0][1], bA1, accA0, 0, 0, 0);    \
    accA1 = __builtin_amdgcn_mfma_f32_16x16x32_bf16(a[1][1], bA1, accA1, 0, 0, 0);    \
    accB0 = __builtin_amdgcn_mfma_f32_16x16x32_bf16(a[0][1], bB1, accB0, 0, 0, 0);    \
    accB1 = __builtin_amdgcn_mfma_f32_16x16x32_bf16(a[1][1], bB1, accB1, 0, 0, 0);    \
    accA0 = __builtin_amdgcn_mfma_f32_16x16x32_bf16(a[0][2], bA2, accA0, 0, 0, 0);    \
    accA1 = __builtin_amdgcn_mfma_f32_16x16x32_bf16(a[1][2], bA2, accA1, 0, 0, 0);    \
    accB0 = __builtin_amdgcn_mfma_f32_16x16x32_bf16(a[0][2], bB2, accB0, 0, 0, 0);    \
    accB1 = __builtin_amdgcn_mfma_f32_16x16x32_bf16(a[1][2], bB2, accB1, 0, 0, 0);    \
    accA0 = __builtin_amdgcn_mfma_f32_16x16x32_bf16(a[0][3], bA3, accA0, 0, 0, 0);    \
    accA1 = __builtin_amdgcn_mfma_f32_16x16x32_bf16(a[1][3], bA3, accA1, 0, 0, 0);    \
    accB0 = __builtin_amdgcn_mfma_f32_16x16x32_bf16(a[0][3], bB3, accB0, 0, 0, 0);    \
    accB1 = __builtin_amdgcn_mfma_f32_16x16x32_bf16(a[1][3], bB3, accB1, 0, 0, 0);

__global__ __launch_bounds__(256, 2) void k_pass1(const unsigned short* __restrict__ xb,
                                                  const int* __restrict__ tg,
                                                  float* __restrict__ mp_part,
                                                  float* __restrict__ mn_part) {
    __shared__ __align__(16) unsigned char smB[JT * 256];  // 16 KB
    __shared__ int ts[CHUNK];                              // 2 KB

    const unsigned char* xc = (const unsigned char*)xb;
    int tid  = threadIdx.x;
    int lane = tid & 63, w = tid >> 6, lr = lane & 15, hi = lane >> 4;
    int bb    = blockIdx.x;
    int chunk = bb & (NCHUNK - 1);
    int rb    = bb >> 4;
    int jbase = chunk * CHUNK;
    int rowbase = rb * BM + w * 32;

    ts[tid]       = tg[jbase + tid];
    ts[tid + 256] = tg[jbase + 256 + tid];

    short8 a[2][4];
#pragma unroll
    for (int rg = 0; rg < 2; ++rg)
#pragma unroll
        for (int ks = 0; ks < 4; ++ks)
            a[rg][ks] = *(const short8*)(xc + (size_t)(rowbase + rg * 16 + lr) * 256 + ks * 64 + hi * 16);

    int trow[2][4];
#pragma unroll
    for (int rg = 0; rg < 2; ++rg)
#pragma unroll
        for (int r = 0; r < 4; ++r)
            trow[rg][r] = tg[rowbase + rg * 16 + hi * 4 + r];

    float mp[2][4], mn[2][4];
#pragma unroll
    for (int rg = 0; rg < 2; ++rg)
#pragma unroll
        for (int r = 0; r < 4; ++r) { mp[rg][r] = SENT; mn[rg][r] = SENT; }

    for (int step = 0; step < NSTEP; ++step) {
        int j0 = jbase + step * JT;
        __syncthreads();  // prior compute done (iter 0: ts ready)
        const unsigned char* src = xc + (size_t)(j0 + w * 16 + lr) * 256 + hi * 16;
#pragma unroll
        for (int r = 0; r < 4; ++r)
            gload16(src + r * 64, smB + w * 4096 + r * 1024);
        __syncthreads();  // tile ready

        bool dstep = (unsigned)(rowbase - j0) < (unsigned)JT;
#pragma unroll
        for (int cgp = 0; cgp < 2; ++cgp) {
            int cg0 = cgp * 2;
            int tjA = ts[step * 64 + cg0 * 16 + lr];
            int tjB = ts[step * 64 + cg0 * 16 + 16 + lr];
            MFMA_PAIR(smB, cg0)
            if (dstep) {
#pragma unroll
                for (int rg = 0; rg < 2; ++rg) {
                    f32x4 aA = (rg == 0) ? accA0 : accA1;
                    f32x4 aB = (rg == 0) ? accB0 : accB1;
                    int base = rowbase + rg * 16 + hi * 4;
                    int dvA = j0 + cg0 * 16 + lr - base;
                    int dvB = dvA + 16;
#pragma unroll
                    for (int r = 0; r < 4; ++r) {
                        bool sA = (tjA == trow[rg][r]);
                        bool sB = (tjB == trow[rg][r]);
                        mp[rg][r] = fmaxf(mp[rg][r], (sA && dvA != r) ? aA[r] : SENT);
                        mn[rg][r] = fmaxf(mn[rg][r], sA ? SENT : aA[r]);
                        mp[rg][r] = fmaxf(mp[rg][r], (sB && dvB != r) ? aB[r] : SENT);
                        mn[rg][r] = fmaxf(mn[rg][r], sB ? SENT : aB[r]);
                    }
                }
            } else {
#pragma unroll
                for (int rg = 0; rg < 2; ++rg) {
                    f32x4 aA = (rg == 0) ? accA0 : accA1;
                    f32x4 aB = (rg == 0) ? accB0 : accB1;
#pragma unroll
                    for (int r = 0; r < 4; ++r) {
                        bool sA = (tjA == trow[rg][r]);
                        bool sB = (tjB == trow[rg][r]);
                        mp[rg][r] = fmaxf(mp[rg][r], sA ? aA[r] : SENT);
                        mn[rg][r] = fmaxf(mn[rg][r], sA ? SENT : aA[r]);
                        mp[rg][r] = fmaxf(mp[rg][r], sB ? aB[r] : SENT);
                        mn[rg][r] = fmaxf(mn[rg][r], sB ? SENT : aB[r]);
                    }
                }
            }
        }
    }

#pragma unroll
    for (int off = 1; off < 16; off <<= 1)
#pragma unroll
        for (int rg = 0; rg < 2; ++rg)
#pragma unroll
            for (int r = 0; r < 4; ++r) {
                mp[rg][r] = fmaxf(mp[rg][r], __shfl_xor(mp[rg][r], off, 64));
                mn[rg][r] = fmaxf(mn[rg][r], __shfl_xor(mn[rg][r], off, 64));
            }
    if (lr == 0) {
#pragma unroll
        for (int rg = 0; rg < 2; ++rg)
#pragma unroll
            for (int r = 0; r < 4; ++r) {
                int row = rowbase + rg * 16 + hi * 4 + r;
                mp_part[chunk * NPTS + row] = mp[rg][r];
                mn_part[chunk * NPTS + row] = mn[rg][r];
            }
    }
}

__global__ __launch_bounds__(256) void k_red1(const float* __restrict__ mp_part,
                                              const float* __restrict__ mn_part,
                                              float* __restrict__ maxpos,
                                              float* __restrict__ maxneg) {
    int row = blockIdx.x * 256 + threadIdx.x;
    float mp = SENT, mn = SENT;
#pragma unroll
    for (int c = 0; c < NCHUNK; ++c) {
        mp = fmaxf(mp, mp_part[c * NPTS + row]);
        mn = fmaxf(mn, mn_part[c * NPTS + row]);
    }
    maxpos[row] = mp;
    maxneg[row] = mn;
}

__global__ __launch_bounds__(256, 2) void k_pass2(const unsigned short* __restrict__ xb,
                                                  const int* __restrict__ tg,
                                                  const float* __restrict__ maxpos,
                                                  const float* __restrict__ maxneg,
                                                  float* __restrict__ sum_part,
                                                  int* __restrict__ flg_part) {
    __shared__ __align__(16) unsigned char smB[JT * 256];
    __shared__ int ts[CHUNK];

    const unsigned char* xc = (const unsigned char*)xb;
    int tid  = threadIdx.x;
    int lane = tid & 63, w = tid >> 6, lr = lane & 15, hi = lane >> 4;
    int bb    = blockIdx.x;
    int chunk = bb & (NCHUNK - 1);
    int rb    = bb >> 4;
    int jbase = chunk * CHUNK;
    int rowbase = rb * BM + w * 32;

    ts[tid]       = tg[jbase + tid];
    ts[tid + 256] = tg[jbase + 256 + tid];

    short8 a[2][4];
#pragma unroll
    for (int rg = 0; rg < 2; ++rg)
#pragma unroll
        for (int ks = 0; ks < 4; ++ks)
            a[rg][ks] = *(const short8*)(xc + (size_t)(rowbase + rg * 16 + lr) * 256 + ks * 64 + hi * 16);

    int trow[2][4];
    float pos_lim[2][4], neg_th[2][4];
#pragma unroll
    for (int rg = 0; rg < 2; ++rg)
#pragma unroll
        for (int r = 0; r < 4; ++r) {
            int row         = rowbase + rg * 16 + hi * 4 + r;
            trow[rg][r]     = tg[row];
            pos_lim[rg][r]  = maxneg[row] + MARGIN;
            neg_th[rg][r]   = fmaxf(NEG_FLOOR, maxpos[row]) - MARGIN;
        }

    float sumP[2][4] = {{0.f,0.f,0.f,0.f},{0.f,0.f,0.f,0.f}};
    float sumN[2][4] = {{0.f,0.f,0.f,0.f},{0.f,0.f,0.f,0.f}};

    for (int step = 0; step < NSTEP; ++step) {
        int j0 = jbase + step * JT;
        __syncthreads();
        const unsigned char* src = xc + (size_t)(j0 + w * 16 + lr) * 256 + hi * 16;
#pragma unroll
        for (int r = 0; r < 4; ++r)
            gload16(src + r * 64, smB + w * 4096 + r * 1024);
        __syncthreads();

        bool dstep = (unsigned)(rowbase - j0) < (unsigned)JT;
#pragma unroll
        for (int cgp = 0; cgp < 2; ++cgp) {
            int cg0 = cgp * 2;
            int tjA = ts[step * 64 + cg0 * 16 + lr];
            int tjB = ts[step * 64 + cg0 * 16 + 16 + lr];
            MFMA_PAIR(smB, cg0)
            if (dstep) {
#pragma unroll
                for (int rg = 0; rg < 2; ++rg) {
                    f32x4 aA = (rg == 0) ? accA0 : accA1;
                    f32x4 aB = (rg == 0) ? accB0 : accB1;
                    int base = rowbase + rg * 16 + hi * 4;
                    int dvA = j0 + cg0 * 16 + lr - base;
                    int dvB = dvA + 16;
#pragma unroll
                    for (int r = 0; r < 4; ++r) {
                        bool sA = (tjA == trow[rg][r]);
                        bool sB = (tjB == trow[rg][r]);
                        float vA = aA[r], vB = aB[r];
                        bool pA = sA && (dvA != r) && (vA < pos_lim[rg][r]);
                        bool nA = (!sA) && (vA > neg_th[rg][r]);
                        bool pB = sB && (dvB != r) && (vB < pos_lim[rg][r]);
                        bool nB = (!sB) && (vB > neg_th[rg][r]);
                        sumP[rg][r] += (pA ? (1.0f - vA) : 0.0f) + (pB ? (1.0f - vB) : 0.0f);
                        sumN[rg][r] += (nA ? vA : 0.0f) + (nB ? vB : 0.0f);
                    }
                }
            } else {
#pragma unroll
                for (int rg = 0; rg < 2; ++rg) {
                    f32x4 aA = (rg == 0) ? accA0 : accA1;
                    f32x4 aB = (rg == 0) ? accB0 : accB1;
#pragma unroll
                    for (int r = 0; r < 4; ++r) {
                        bool sA = (tjA == trow[rg][r]);
                        bool sB = (tjB == trow[rg][r]);
                        float vA = aA[r], vB = aB[r];
                        bool pA = sA && (vA < pos_lim[rg][r]);
                        bool nA = (!sA) && (vA > neg_th[rg][r]);
                        bool pB = sB && (vB < pos_lim[rg][r]);
                        bool nB = (!sB) && (vB > neg_th[rg][r]);
                        sumP[rg][r] += (pA ? (1.0f - vA) : 0.0f) + (pB ? (1.0f - vB) : 0.0f);
                        sumN[rg][r] += (nA ? vA : 0.0f) + (nB ? vB : 0.0f);
                    }
                }
            }
        }
    }

    // any selected negative <=> sumN > 0 (selected negs have s > 0.4)
    float sum[2][4];
    int an = 0;
#pragma unroll
    for (int rg = 0; rg < 2; ++rg)
#pragma unroll
        for (int r = 0; r < 4; ++r) {
            sum[rg][r] = sumP[rg][r] + sumN[rg][r];
            an |= (sumN[rg][r] > 0.f) ? (1 << (rg * 4 + r)) : 0;
        }

#pragma unroll
    for (int off = 1; off < 16; off <<= 1) {
        an |= __shfl_xor(an, off, 64);
#pragma unroll
        for (int rg = 0; rg < 2; ++rg)
#pragma unroll
            for (int r = 0; r < 4; ++r)
                sum[rg][r] += __shfl_xor(sum[rg][r], off, 64);
    }
    if (lr == 0) {
#pragma unroll
        for (int rg = 0; rg < 2; ++rg)
#pragma unroll
            for (int r = 0; r < 4; ++r) {
                int row = rowbase + rg * 16 + hi * 4 + r;
                sum_part[chunk * NPTS + row] = sum[rg][r];
                flg_part[chunk * NPTS + row] = (an >> (rg * 4 + r)) & 1;
            }
    }
}

__global__ __launch_bounds__(256) void k_red2(const float* __restrict__ maxpos,
                                              const float* __restrict__ sum_part,
                                              const int* __restrict__ flg_part,
                                              float* __restrict__ blksum,
                                              float* __restrict__ blkcnt) {
    __shared__ float sf[256];
    __shared__ int   si[256];
    int t   = threadIdx.x;
    int row = blockIdx.x * 256 + t;

    bool hp = maxpos[row] > -1e29f;
    float rs = 0.f;
    int   fl = 0;
#pragma unroll
    for (int ch = 0; ch < NCHUNK; ++ch) {
        rs += sum_part[ch * NPTS + row];
        fl |= flg_part[ch * NPTS + row];
    }
    sf[t] = hp ? rs : 0.f;
    si[t] = (hp && fl) ? 1 : 0;
    __syncthreads();
    for (int off = 128; off > 0; off >>= 1) {
        if (t < off) { sf[t] += sf[t + off]; si[t] += si[t + off]; }
        __syncthreads();
    }
    if (t == 0) {
        blksum[blockIdx.x] = sf[0];
        blkcnt[blockIdx.x] = (float)si[0];
    }
}

__global__ __launch_bounds__(64) void k_final(const float* __restrict__ blksum,
                                              const float* __restrict__ blkcnt,
                                              float* __restrict__ out) {
    int t = threadIdx.x;
    float s = (t < NRB) ? blksum[t] : 0.f;
    float c = (t < NRB) ? blkcnt[t] : 0.f;
#pragma unroll
    for (int off = 32; off > 0; off >>= 1) {
        s += __shfl_xor(s, off, 64);
        c += __shfl_xor(c, off, 64);
    }
    if (t == 0) {
        out[0] = s / (float)NPTS;
        out[1] = c;
    }
}

extern "C" void kernel_launch(void* const* d_in, const int* in_sizes, int n_in,
                              void* d_out, int out_size, void* d_ws, size_t ws_size,
                              hipStream_t stream) {
    const float* x  = (const float*)d_in[0];
    const int*   tg = (const int*)d_in[1];
    float* out = (float*)d_out;

    unsigned short* xb = (unsigned short*)d_ws;
    char* base = (char*)d_ws + (size_t)NPTS * DDIM * 2;
    float* partA = (float*)(base);                                  // mp_part / sum_part
    float* partB = (float*)(base + (size_t)NCHUNK * NPTS * 4);      // mn_part / flg_part
    float* maxpos = (float*)(base + 2 * (size_t)NCHUNK * NPTS * 4);
    float* maxneg = (float*)(base + 2 * (size_t)NCHUNK * NPTS * 4 + NPTS * 4);
    float* blksum = (float*)(base + 2 * (size_t)NCHUNK * NPTS * 4 + 2 * NPTS * 4);
    float* blkcnt = blksum + NRB;

    k_convert<<<(NPTS * DDIM / 4) / 256, 256, 0, stream>>>((const uint4v*)x, (ushort4v*)xb);
    k_pass1<<<(NPTS / BM) * NCHUNK, 256, 0, stream>>>(xb, tg, partA, partB);
    k_red1<<<NPTS / 256, 256, 0, stream>>>(partA, partB, maxpos, maxneg);
    k_pass2<<<(NPTS / BM) * NCHUNK, 256, 0, stream>>>(xb, tg, maxpos, maxneg, partA, (int*)partB);
    k_red2<<<NRB, 256, 0, stream>>>(maxpos, partA, (const int*)partB, blksum, blkcnt);
    k_final<<<1, 64, 0, stream>>>(blksum, blkcnt, out);
}